// Round 5
// baseline (335.724 us; speedup 1.0000x reference)
//
#include <hip/hip_runtime.h>
#include <stdint.h>

typedef short short8 __attribute__((ext_vector_type(8)));
typedef float f32x4 __attribute__((ext_vector_type(4)));

#define D 128
#define LOG2E 1.44269504088896340736f

__device__ __forceinline__ unsigned short f2bf(float f) {
    union { float f; unsigned u; } v; v.f = f;
    unsigned u = v.u;
    unsigned r = (u + 0x7FFFu + ((u >> 16) & 1u)) >> 16;  // RNE
    return (unsigned short)r;
}

// pack two f32 -> one u32 of two bf16 (round-half-up via +0x8000, then v_perm)
__device__ __forceinline__ unsigned packbf(float x, float y) {
    unsigned ux = __float_as_uint(x) + 0x8000u;
    unsigned uy = __float_as_uint(y) + 0x8000u;
    return __builtin_amdgcn_perm(uy, ux, 0x07060302u);
}

// DPP butterfly add within 16-lane groups: xor1,xor2 via quad_perm;
// xor4 = row_half_mirror (0x141), xor8 = row_mirror (0x140) — valid because
// lower bits are already uniform when applied (7-k == 7^k, 15-k == 15^k).
template <int C>
__device__ __forceinline__ float dpp_add(float x) {
    int y = __builtin_amdgcn_update_dpp(0, __float_as_int(x), C, 0xF, 0xF, true);
    return x + __int_as_float(y);
}
__device__ __forceinline__ float red16(float x) {
    x = dpp_add<0xB1>(x);   // xor1
    x = dpp_add<0x4E>(x);   // xor2
    x = dpp_add<0x141>(x);  // xor4 (row_half_mirror)
    x = dpp_add<0x140>(x);  // xor8 (row_mirror)
    return x;
}

// HBM -> LDS direct (16B per lane). LDS dest must be linear base + lane*16.
__device__ __forceinline__ void gld16(const float* g, float* l) {
    __builtin_amdgcn_global_load_lds(
        (const __attribute__((address_space(1))) void*)g,
        (__attribute__((address_space(3))) void*)l, 16, 0, 0);
}

// ---------------------------------------------------------------------------
// Kernel 1: pre-pack (Wu * log2e) as bf16 MFMA B-fragments.
// t = nt*256 + kk*64 + lane holds B[k][col], col = nt*16+(lane&15),
// k = kk*32+(lane>>4)*8+j  (B[k][col] = Wu[col][k], u = f @ Wu^T)
// ---------------------------------------------------------------------------
__global__ __launch_bounds__(256) void pack_wu(const float* __restrict__ Wu,
                                               short8* __restrict__ frag) {
    int tid = blockIdx.x * 256 + threadIdx.x;
    int nt = tid >> 8, kk = (tid >> 6) & 3, l = tid & 63;
    int col = nt * 16 + (l & 15);
    int kb  = kk * 32 + ((l >> 4) * 8);
    short8 o;
#pragma unroll
    for (int j = 0; j < 8; ++j) o[j] = (short)f2bf(Wu[col * D + kb + j] * LOG2E);
    frag[tid] = o;
}

// ---------------------------------------------------------------------------
// Kernel 2: per-graph gate factors  c = 2^{-(Wv·x_last + bu)·log2e}.
// 16 graphs per block; each Wv float4 loaded once serves 4 graphs (both
// streams share the same Wv row) -> Wv stays L1/L2-hot.
// ---------------------------------------------------------------------------
__global__ __launch_bounds__(256) void gate_k(const float* __restrict__ xI,
                                              const float* __restrict__ xV,
                                              const float* __restrict__ Wv,
                                              const float* __restrict__ bu,
                                              const int* __restrict__ lastn,
                                              float* __restrict__ cIb,
                                              float* __restrict__ cVb, int B) {
    __shared__ __align__(16) float xs[4][2][D];
    int t = threadIdx.x, h = t & 127, st = t >> 7;
    float bias = bu[h];
    const float4* wv4 = (const float4*)(Wv + (size_t)h * D);
    const float* src = st ? xV : xI;
    float* dst = st ? cVb : cIb;
    int g0 = blockIdx.x * 16;
    for (int p = 0; p < 4; ++p) {
        int gb = g0 + p * 4;
#pragma unroll
        for (int j = 0; j < 4; ++j) {
            int gg = gb + j; if (gg >= B) gg = B - 1;
            xs[j][st][h] = src[(size_t)lastn[gg] * D + h];
        }
        __syncthreads();
        const float4* x0 = (const float4*)xs[0][st];
        const float4* x1 = (const float4*)xs[1][st];
        const float4* x2 = (const float4*)xs[2][st];
        const float4* x3 = (const float4*)xs[3][st];
        float a0 = 0.f, a1 = 0.f, a2 = 0.f, a3 = 0.f;
#pragma unroll
        for (int i = 0; i < 32; ++i) {
            float4 w = wv4[i], b;
            b = x0[i]; a0 += w.x*b.x + w.y*b.y + w.z*b.z + w.w*b.w;
            b = x1[i]; a1 += w.x*b.x + w.y*b.y + w.z*b.z + w.w*b.w;
            b = x2[i]; a2 += w.x*b.x + w.y*b.y + w.z*b.z + w.w*b.w;
            b = x3[i]; a3 += w.x*b.x + w.y*b.y + w.z*b.z + w.w*b.w;
        }
        if (gb + 0 < B) dst[(size_t)(gb+0)*D + h] = __builtin_amdgcn_exp2f(-(a0+bias)*LOG2E);
        if (gb + 1 < B) dst[(size_t)(gb+1)*D + h] = __builtin_amdgcn_exp2f(-(a1+bias)*LOG2E);
        if (gb + 2 < B) dst[(size_t)(gb+2)*D + h] = __builtin_amdgcn_exp2f(-(a2+bias)*LOG2E);
        if (gb + 3 < B) dst[(size_t)(gb+3)*D + h] = __builtin_amdgcn_exp2f(-(a3+bias)*LOG2E);
        __syncthreads();
    }
}

// ---------------------------------------------------------------------------
// Kernel 3: fused main. Block per graph, 4 waves striding 16-row chunks.
// Rows: HBM->LDS via global_load_lds (swizzled source, linear dest).
// Wu B-fragments: read per-tile from GLOBAL (L1/L2-hot, same 32KB for every
// wave on the chip), double-buffered 2 tiles in regs -> LDS is only 37KB
// -> 4 blocks/CU (occupancy capped by VGPR at ~3 waves/SIMD).
// sigmoid via shared exp2: sigma(u+v) = 1/(1 + 2^-u * c), c = 2^-v (precomp).
// ---------------------------------------------------------------------------
__global__ __launch_bounds__(256) void attn_main(
    const float* __restrict__ xI, const float* __restrict__ xV,
    const float* __restrict__ We, const int* __restrict__ lastn,
    const float* __restrict__ cIb, const float* __restrict__ cVb,
    const short8* __restrict__ fragG, float* __restrict__ out, int B) {
    __shared__ __align__(16) float rbuf[4][2048];        // 32 KB row chunks
    __shared__ float cmbA[2][4][D];                      // combine
    __shared__ float cmbM[2][4], cmbL[2][4];

    int t = threadIdx.x, lane = t & 63, w = t >> 6;
    int g = blockIdx.x;

    int s = (g == 0) ? 0 : (lastn[g - 1] + 1);
    int n = lastn[g] + 1 - s;                     // >= 1

    // per-lane constants: col = nt*16 + (lane&15)
    float WeR[8], cIr[8], cVr[8];
#pragma unroll
    for (int nt = 0; nt < 8; ++nt) {
        int col = nt * 16 + (lane & 15);
        WeR[nt] = We[col] * LOG2E;
        cIr[nt] = cIb[(size_t)g * D + col];
        cVr[nt] = cVb[(size_t)g * D + col];
    }

    int ch = (n + 15) >> 4;
    int total = 2 * ch;
    float* rb = &rbuf[w][0];
    const char* rbc = (const char*)rb;

    // precomputed per-lane offsets -----------------------------------------
    int loff[8];                       // global float-offset per staging load
#pragma unroll
    for (int i = 0; i < 8; ++i) {
        int row = (i << 1) + (lane >> 5);
        loff[i] = (row << 7) + (((lane & 31) ^ (row & 7)) << 2);
    }
    int arow = lane & 15;
    int sw = (arow & 7) << 4;
    int ab0 = ((arow << 9) + ((lane >> 4) << 5)) ^ sw;        // af base (lo 16B)
    int ab1 = ((arow << 9) + ((lane >> 4) << 5) + 16) ^ sw;   // af base (hi 16B)
    int frb[8];                        // fr bases per (r&7)
#pragma unroll
    for (int j = 0; j < 8; ++j) frb[j] = (lane << 2) ^ (j << 4);

    // issue 8 global_load_lds for chunk cc into this wave's buffer.
    auto issue = [&](int cc) {
        int hf = (cc >= ch) ? 1 : 0;
        const float* sp = hf ? xV : xI;
        int bb = (cc - hf * ch) << 4;
        if (bb + 16 <= n) {            // interior: no clamps
            const float* pb = sp + ((size_t)(s + bb) << 7);
#pragma unroll
            for (int i = 0; i < 8; ++i)
                gld16(pb + loff[i], rb + (i << 8) + (lane << 2));
        } else {                       // tail: clamp rows (masked later)
#pragma unroll
            for (int i = 0; i < 8; ++i) {
                int row = (i << 1) + (lane >> 5);
                int rr = bb + row; if (rr > n - 1) rr = n - 1;
                int lu = (lane & 31) ^ (row & 7);
                gld16(sp + (size_t)(s + rr) * D + (lu << 2),
                      rb + (i << 8) + (lane << 2));
            }
        }
    };

    if (w < total) issue(w);

    float mI = -__builtin_inff(), mV = -__builtin_inff();
    float lIs = 0.f, lVs = 0.f;
    float aI0 = 0.f, aI1 = 0.f, aV0 = 0.f, aV1 = 0.f;

    for (int c = w; c < total; c += 4) {
        int hf = (c >= ch) ? 1 : 0;
        int base = (c - hf * ch) << 4;

        asm volatile("s_waitcnt vmcnt(0)" ::: "memory");   // chunk c landed
        __builtin_amdgcn_sched_barrier(0);

        // ---- A fragments from LDS ----
        short8 af[4];
#pragma unroll
        for (int kk = 0; kk < 4; ++kk) {
            float4 f0 = *(const float4*)(rbc + ab0 + (kk << 7));
            float4 f1 = *(const float4*)(rbc + ab1 + (kk << 7));
            union { unsigned u[4]; short8 s8; } cv;
            cv.u[0] = packbf(f0.x, f0.y);
            cv.u[1] = packbf(f0.z, f0.w);
            cv.u[2] = packbf(f1.x, f1.y);
            cv.u[3] = packbf(f1.z, f1.w);
            af[kk] = cv.s8;
        }
        // ---- accumulate operands into regs (frees the LDS buffer) ----
        float fr0[16], fr1[16];
#pragma unroll
        for (int r = 0; r < 16; ++r) {
            const char* p = rbc + frb[r & 7] + (r << 9);
            fr0[r] = *(const float*)p;
            fr1[r] = *(const float*)(p + 256);
        }
        asm volatile("s_waitcnt lgkmcnt(0)" ::: "memory"); // LDS reads done
        __builtin_amdgcn_sched_barrier(0);

        // ---- GEMM + gate epilogue; B-tiles streamed from global (L1-hot),
        //      double-buffered; staging for c+4 issued under the last tile.
        float pI[4] = {0.f, 0.f, 0.f, 0.f}, pV[4] = {0.f, 0.f, 0.f, 0.f};
        short8 bf[2][4];
#pragma unroll
        for (int kk = 0; kk < 4; ++kk) bf[0][kk] = fragG[(kk << 6) + lane];
#pragma unroll
        for (int nt = 0; nt < 8; ++nt) {
            if (nt < 7) {
#pragma unroll
                for (int kk = 0; kk < 4; ++kk)
                    bf[(nt + 1) & 1][kk] = fragG[(nt + 1) * 256 + (kk << 6) + lane];
            } else if (c + 4 < total) {
                issue(c + 4);          // prefetch rows (hidden by tail compute)
            }
            f32x4 dacc = {0.f, 0.f, 0.f, 0.f};
#pragma unroll
            for (int kk = 0; kk < 4; ++kk)
                dacc = __builtin_amdgcn_mfma_f32_16x16x32_bf16(
                    af[kk], bf[nt & 1][kk], dacc, 0, 0, 0);
#pragma unroll
            for (int q = 0; q < 4; ++q) {
                float tt = __builtin_amdgcn_exp2f(-dacc[q]);   // shared exp2
                float dI = fmaf(tt, cIr[nt], 1.f);
                float dV = fmaf(tt, cVr[nt], 1.f);
                pI[q] = fmaf(WeR[nt], __builtin_amdgcn_rcpf(dI), pI[q]);
                pV[q] = fmaf(WeR[nt], __builtin_amdgcn_rcpf(dV), pV[q]);
            }
        }
        // reduce across 16 lanes (cols) via DPP; mask invalid rows (tail only)
#pragma unroll
        for (int q = 0; q < 4; ++q) { pI[q] = red16(pI[q]); pV[q] = red16(pV[q]); }
        if (base + 16 > n) {
#pragma unroll
            for (int q = 0; q < 4; ++q) {
                int r = ((lane >> 4) << 2) + q;
                if (base + r >= n) { pI[q] = -__builtin_inff(); pV[q] = -__builtin_inff(); }
            }
        }
        float cmI = fmaxf(fmaxf(pI[0], pI[1]), fmaxf(pI[2], pI[3]));
        float cmV = fmaxf(fmaxf(pV[0], pV[1]), fmaxf(pV[2], pV[3]));
        cmI = fmaxf(cmI, __shfl_xor(cmI, 16)); cmI = fmaxf(cmI, __shfl_xor(cmI, 32));
        cmV = fmaxf(cmV, __shfl_xor(cmV, 16)); cmV = fmaxf(cmV, __shfl_xor(cmV, 32));

        float mnI = fmaxf(mI, cmI), mnV = fmaxf(mV, cmV);
        float scI = __builtin_amdgcn_exp2f(mI - mnI);
        float scV = __builtin_amdgcn_exp2f(mV - mnV);
        lIs *= scI; lVs *= scV;
        aI0 *= scI; aI1 *= scI; aV0 *= scV; aV1 *= scV;

        float wIq[4], wVq[4];
#pragma unroll
        for (int q = 0; q < 4; ++q) {
            wIq[q] = __builtin_amdgcn_exp2f(pI[q] - mnI);   // 0 for masked rows
            wVq[q] = __builtin_amdgcn_exp2f(pV[q] - mnV);
        }
        float sIq = wIq[0] + wIq[1] + wIq[2] + wIq[3];
        float sVq = wVq[0] + wVq[1] + wVq[2] + wVq[3];
        sIq += __shfl_xor(sIq, 16); sIq += __shfl_xor(sIq, 32);
        sVq += __shfl_xor(sVq, 16); sVq += __shfl_xor(sVq, 32);
        lIs += sIq; lVs += sVq;

        // weighted accumulate from registers
#pragma unroll
        for (int r = 0; r < 16; ++r) {
            float wI = __shfl(wIq[r & 3], (r >> 2) << 4);
            float wV = __shfl(wVq[r & 3], (r >> 2) << 4);
            aI0 = fmaf(wI, fr0[r], aI0); aI1 = fmaf(wI, fr1[r], aI1);
            aV0 = fmaf(wV, fr0[r], aV0); aV1 = fmaf(wV, fr1[r], aV1);
        }
        mI = mnI; mV = mnV;
    }

    // ---- cross-wave flash combine ----
    cmbA[0][w][lane] = aI0; cmbA[0][w][lane + 64] = aI1;
    cmbA[1][w][lane] = aV0; cmbA[1][w][lane + 64] = aV1;
    if (lane == 0) {
        cmbM[0][w] = mI; cmbL[0][w] = lIs;
        cmbM[1][w] = mV; cmbL[1][w] = lVs;
    }
    __syncthreads();
    {
        int st = t >> 7, d = t & 127;
        float M = fmaxf(fmaxf(cmbM[st][0], cmbM[st][1]),
                        fmaxf(cmbM[st][2], cmbM[st][3]));
        float Ls = 0.f, A = 0.f;
#pragma unroll
        for (int ww = 0; ww < 4; ++ww) {
            float e = __builtin_amdgcn_exp2f(cmbM[st][ww] - M);  // 0 for idle waves
            Ls += cmbL[st][ww] * e;
            A  += cmbA[st][ww][d] * e;
        }
        out[(size_t)st * B * D + (size_t)g * D + d] = A * __builtin_amdgcn_rcpf(Ls);
    }
}

// ---------------------------------------------------------------------------
extern "C" void kernel_launch(void* const* d_in, const int* in_sizes, int n_in,
                              void* d_out, int out_size, void* d_ws, size_t ws_size,
                              hipStream_t stream) {
    const float* xI    = (const float*)d_in[0];
    const float* xV    = (const float*)d_in[1];
    const float* Wu    = (const float*)d_in[2];
    const float* bu    = (const float*)d_in[3];
    const float* Wv    = (const float*)d_in[4];
    const float* We    = (const float*)d_in[5];
    // d_in[6] = seg_ids (unused: segments contiguous, last_nodes suffices)
    const int*   lastn = (const int*)d_in[7];
    const int B = in_sizes[7];               // 8192

    float*  cIb   = (float*)d_ws;
    float*  cVb   = cIb + (size_t)B * D;
    short8* fragW = (short8*)(cVb + (size_t)B * D);

    pack_wu<<<8, 256, 0, stream>>>(Wu, fragW);
    gate_k<<<(B + 15) / 16, 256, 0, stream>>>(xI, xV, Wv, bu, lastn, cIb, cVb, B);
    attn_main<<<B, 256, 0, stream>>>(xI, xV, We, lastn, cIb, cVb, fragW,
                                     (float*)d_out, B);
}

// Round 6
// 220.834 us; speedup vs baseline: 1.5203x; 1.5203x over previous
//
#include <hip/hip_runtime.h>
#include <stdint.h>

typedef short short8 __attribute__((ext_vector_type(8)));
typedef float f32x4 __attribute__((ext_vector_type(4)));

#define D 128
#define LOG2E 1.44269504088896340736f

__device__ __forceinline__ unsigned short f2bf(float f) {
    union { float f; unsigned u; } v; v.f = f;
    unsigned u = v.u;
    unsigned r = (u + 0x7FFFu + ((u >> 16) & 1u)) >> 16;  // RNE
    return (unsigned short)r;
}

// pack two f32 -> one u32 of two bf16 (round-half-up via +0x8000, then v_perm)
__device__ __forceinline__ unsigned packbf(float x, float y) {
    unsigned ux = __float_as_uint(x) + 0x8000u;
    unsigned uy = __float_as_uint(y) + 0x8000u;
    return __builtin_amdgcn_perm(uy, ux, 0x07060302u);
}

// DPP butterfly add within 16-lane groups (verified round 5):
// xor1,xor2 via quad_perm; xor4 = row_half_mirror; xor8 = row_mirror.
template <int C>
__device__ __forceinline__ float dpp_add(float x) {
    int y = __builtin_amdgcn_update_dpp(0, __float_as_int(x), C, 0xF, 0xF, true);
    return x + __int_as_float(y);
}
__device__ __forceinline__ float red16(float x) {
    x = dpp_add<0xB1>(x);
    x = dpp_add<0x4E>(x);
    x = dpp_add<0x141>(x);
    x = dpp_add<0x140>(x);
    return x;
}

// ---------------------------------------------------------------------------
// Kernel 1: pre-pack (Wu * log2e) as bf16 MFMA B-fragments.
// t = nt*256 + kk*64 + lane holds B[k][col], col = nt*16+(lane&15),
// k = kk*32+(lane>>4)*8+j  (B[k][col] = Wu[col][k], u = f @ Wu^T)
// ---------------------------------------------------------------------------
__global__ __launch_bounds__(256) void pack_wu(const float* __restrict__ Wu,
                                               short8* __restrict__ frag) {
    int tid = blockIdx.x * 256 + threadIdx.x;
    int nt = tid >> 8, kk = (tid >> 6) & 3, l = tid & 63;
    int col = nt * 16 + (l & 15);
    int kb  = kk * 32 + ((l >> 4) * 8);
    short8 o;
#pragma unroll
    for (int j = 0; j < 8; ++j) o[j] = (short)f2bf(Wu[col * D + kb + j] * LOG2E);
    frag[tid] = o;
}

// ---------------------------------------------------------------------------
// Kernel 2: per-graph gate factors  c = 2^{-(Wv·x_last + bu)·log2e}.
// 16 graphs per block; Wv stays L1/L2-hot. (Validated round 5: saved ~28us.)
// ---------------------------------------------------------------------------
__global__ __launch_bounds__(256) void gate_k(const float* __restrict__ xI,
                                              const float* __restrict__ xV,
                                              const float* __restrict__ Wv,
                                              const float* __restrict__ bu,
                                              const int* __restrict__ lastn,
                                              float* __restrict__ cIb,
                                              float* __restrict__ cVb, int B) {
    __shared__ __align__(16) float xs[4][2][D];
    int t = threadIdx.x, h = t & 127, st = t >> 7;
    float bias = bu[h];
    const float4* wv4 = (const float4*)(Wv + (size_t)h * D);
    const float* src = st ? xV : xI;
    float* dst = st ? cVb : cIb;
    int g0 = blockIdx.x * 16;
    for (int p = 0; p < 4; ++p) {
        int gb = g0 + p * 4;
#pragma unroll
        for (int j = 0; j < 4; ++j) {
            int gg = gb + j; if (gg >= B) gg = B - 1;
            xs[j][st][h] = src[(size_t)lastn[gg] * D + h];
        }
        __syncthreads();
        const float4* x0 = (const float4*)xs[0][st];
        const float4* x1 = (const float4*)xs[1][st];
        const float4* x2 = (const float4*)xs[2][st];
        const float4* x3 = (const float4*)xs[3][st];
        float a0 = 0.f, a1 = 0.f, a2 = 0.f, a3 = 0.f;
#pragma unroll
        for (int i = 0; i < 32; ++i) {
            float4 w = wv4[i], b;
            b = x0[i]; a0 += w.x*b.x + w.y*b.y + w.z*b.z + w.w*b.w;
            b = x1[i]; a1 += w.x*b.x + w.y*b.y + w.z*b.z + w.w*b.w;
            b = x2[i]; a2 += w.x*b.x + w.y*b.y + w.z*b.z + w.w*b.w;
            b = x3[i]; a3 += w.x*b.x + w.y*b.y + w.z*b.z + w.w*b.w;
        }
        if (gb + 0 < B) dst[(size_t)(gb+0)*D + h] = __builtin_amdgcn_exp2f(-(a0+bias)*LOG2E);
        if (gb + 1 < B) dst[(size_t)(gb+1)*D + h] = __builtin_amdgcn_exp2f(-(a1+bias)*LOG2E);
        if (gb + 2 < B) dst[(size_t)(gb+2)*D + h] = __builtin_amdgcn_exp2f(-(a2+bias)*LOG2E);
        if (gb + 3 < B) dst[(size_t)(gb+3)*D + h] = __builtin_amdgcn_exp2f(-(a3+bias)*LOG2E);
        __syncthreads();
    }
}

// ---------------------------------------------------------------------------
// Kernel 3: fused main. Block per graph, 4 waves striding 16-row chunks.
// NO row staging: A-fragments gathered directly from global (line-coalesced,
// read-once — round-1-verified pattern); accumulate re-reads hit L1/L2.
// LDS = 32KB bfrag + 5KB -> 4 blocks/CU (2x round-4 occupancy).
// sigmoid pair shares one exp2 AND one rcp: r=rcp(dI*dV); sI=dV*r; sV=dI*r.
// Weight broadcast via tiny per-wave LDS table instead of 32 ds_bpermute.
// ---------------------------------------------------------------------------
__global__ __launch_bounds__(256) void attn_main(
    const float* __restrict__ xI, const float* __restrict__ xV,
    const float* __restrict__ We, const int* __restrict__ lastn,
    const float* __restrict__ cIb, const float* __restrict__ cVb,
    const short8* __restrict__ fragG, float* __restrict__ out, int B) {
    __shared__ short8 bfrag[2048];          // 32 KB Wu fragments
    __shared__ __align__(16) float wt[4][16][2];  // per-wave weight table
    __shared__ float cmbA[2][4][D];         // combine
    __shared__ float cmbM[2][4], cmbL[2][4];

    int t = threadIdx.x, lane = t & 63, w = t >> 6;
    int g = blockIdx.x;

    {   // stage Wu fragments (contiguous 16B/lane -> conflict-free b128)
        const uint4* srcf = (const uint4*)fragG;
        uint4* dst = (uint4*)bfrag;
#pragma unroll
        for (int i = 0; i < 8; ++i) dst[i * 256 + t] = srcf[i * 256 + t];
    }

    int s = (g == 0) ? 0 : (lastn[g - 1] + 1);
    int n = lastn[g] + 1 - s;                     // >= 1

    // per-lane constants: col = nt*16 + (lane&15)
    float WeR[8], cIr[8], cVr[8];
#pragma unroll
    for (int nt = 0; nt < 8; ++nt) {
        int col = nt * 16 + (lane & 15);
        WeR[nt] = We[col] * LOG2E;
        cIr[nt] = cIb[(size_t)g * D + col];
        cVr[nt] = cVb[(size_t)g * D + col];
    }
    __syncthreads();

    float mI = -__builtin_inff(), mV = -__builtin_inff();
    float lIs = 0.f, lVs = 0.f;
    float aI0 = 0.f, aI1 = 0.f, aV0 = 0.f, aV1 = 0.f;

    int ch = (n + 15) >> 4;
    int total = 2 * ch;

    for (int c = w; c < total; c += 4) {
        int hf = (c >= ch) ? 1 : 0;
        const float* srcs = (hf ? xV : xI) + ((size_t)s << 7);
        int base = (c - hf * ch) << 4;

        // ---- A fragments direct from global: row = lane&15,
        //      dims = (lane>>4)*8 + kk*32 + j  (32B/lane/kk, full lines) ----
        int arow = base + (lane & 15);
        if (arow > n - 1) arow = n - 1;           // clamp (masked later)
        const float* rp = srcs + ((size_t)arow << 7) + ((lane >> 4) << 3);
        short8 af[4];
#pragma unroll
        for (int kk = 0; kk < 4; ++kk) {
            float4 f0 = *(const float4*)(rp + kk * 32);
            float4 f1 = *(const float4*)(rp + kk * 32 + 4);
            union { unsigned u[4]; short8 s8; } cv;
            cv.u[0] = packbf(f0.x, f0.y);
            cv.u[1] = packbf(f0.z, f0.w);
            cv.u[2] = packbf(f1.x, f1.y);
            cv.u[3] = packbf(f1.z, f1.w);
            af[kk] = cv.s8;
        }

        // ---- GEMM + gate epilogue (shared exp2 + shared rcp) ----
        float pI[4] = {0.f, 0.f, 0.f, 0.f}, pV[4] = {0.f, 0.f, 0.f, 0.f};
#pragma unroll
        for (int nt = 0; nt < 8; ++nt) {
            f32x4 dacc = {0.f, 0.f, 0.f, 0.f};
#pragma unroll
            for (int kk = 0; kk < 4; ++kk)
                dacc = __builtin_amdgcn_mfma_f32_16x16x32_bf16(
                    af[kk], bfrag[nt * 256 + kk * 64 + lane], dacc, 0, 0, 0);
#pragma unroll
            for (int q = 0; q < 4; ++q) {
                float t2 = __builtin_amdgcn_exp2f(-dacc[q]);
                float dI = fmaf(t2, cIr[nt], 1.f);
                float dV = fmaf(t2, cVr[nt], 1.f);
                float rr = __builtin_amdgcn_rcpf(dI * dV);
                pI[q] = fmaf(WeR[nt], dV * rr, pI[q]);   // WeR/dI
                pV[q] = fmaf(WeR[nt], dI * rr, pV[q]);   // WeR/dV
            }
        }
        // reduce across 16 lanes (cols) via DPP; mask invalid rows (tail only)
#pragma unroll
        for (int q = 0; q < 4; ++q) { pI[q] = red16(pI[q]); pV[q] = red16(pV[q]); }
        if (base + 16 > n) {
#pragma unroll
            for (int q = 0; q < 4; ++q) {
                int r = ((lane >> 4) << 2) + q;
                if (base + r >= n) { pI[q] = -__builtin_inff(); pV[q] = -__builtin_inff(); }
            }
        }
        float cmI = fmaxf(fmaxf(pI[0], pI[1]), fmaxf(pI[2], pI[3]));
        float cmV = fmaxf(fmaxf(pV[0], pV[1]), fmaxf(pV[2], pV[3]));
        cmI = fmaxf(cmI, __shfl_xor(cmI, 16)); cmI = fmaxf(cmI, __shfl_xor(cmI, 32));
        cmV = fmaxf(cmV, __shfl_xor(cmV, 16)); cmV = fmaxf(cmV, __shfl_xor(cmV, 32));

        float mnI = fmaxf(mI, cmI), mnV = fmaxf(mV, cmV);
        float scI = __builtin_amdgcn_exp2f(mI - mnI);
        float scV = __builtin_amdgcn_exp2f(mV - mnV);
        lIs *= scI; lVs *= scV;
        aI0 *= scI; aI1 *= scI; aV0 *= scV; aV1 *= scV;

        float wIq[4], wVq[4];
#pragma unroll
        for (int q = 0; q < 4; ++q) {
            wIq[q] = __builtin_amdgcn_exp2f(pI[q] - mnI);   // 0 for masked rows
            wVq[q] = __builtin_amdgcn_exp2f(pV[q] - mnV);
        }
        float sIq = wIq[0] + wIq[1] + wIq[2] + wIq[3];
        float sVq = wVq[0] + wVq[1] + wVq[2] + wVq[3];
        sIq += __shfl_xor(sIq, 16); sIq += __shfl_xor(sIq, 32);
        sVq += __shfl_xor(sVq, 16); sVq += __shfl_xor(sVq, 32);
        lIs += sIq; lVs += sVq;

        // ---- publish weights to per-wave LDS table (all 16 lanes of a
        //      group hold the sums after red16; lane g*16 writes rows 4g..) --
        if ((lane & 15) == 0) {
            int gq = lane >> 4;
            float4 w0 = {wIq[0], wVq[0], wIq[1], wVq[1]};
            float4 w1 = {wIq[2], wVq[2], wIq[3], wVq[3]};
            *(float4*)&wt[w][gq * 4 + 0][0] = w0;
            *(float4*)&wt[w][gq * 4 + 2][0] = w1;
        }
        asm volatile("" ::: "memory");   // keep wt reads after writes

        // ---- weighted accumulate; rows re-read from L1/L2 (just touched) --
#pragma unroll
        for (int r = 0; r < 16; ++r) {
            int rr = base + r; if (rr > n - 1) rr = n - 1;
            const float* p = srcs + ((size_t)rr << 7);
            float f0 = p[lane], f1 = p[64 + lane];
            float wI = wt[w][r][0], wV = wt[w][r][1];
            aI0 = fmaf(wI, f0, aI0); aI1 = fmaf(wI, f1, aI1);
            aV0 = fmaf(wV, f0, aV0); aV1 = fmaf(wV, f1, aV1);
        }
        mI = mnI; mV = mnV;
    }

    // ---- cross-wave flash combine ----
    cmbA[0][w][lane] = aI0; cmbA[0][w][lane + 64] = aI1;
    cmbA[1][w][lane] = aV0; cmbA[1][w][lane + 64] = aV1;
    if (lane == 0) {
        cmbM[0][w] = mI; cmbL[0][w] = lIs;
        cmbM[1][w] = mV; cmbL[1][w] = lVs;
    }
    __syncthreads();
    {
        int st = t >> 7, d = t & 127;
        float M = fmaxf(fmaxf(cmbM[st][0], cmbM[st][1]),
                        fmaxf(cmbM[st][2], cmbM[st][3]));
        float Ls = 0.f, A = 0.f;
#pragma unroll
        for (int ww = 0; ww < 4; ++ww) {
            float e = __builtin_amdgcn_exp2f(cmbM[st][ww] - M);  // 0 for idle waves
            Ls += cmbL[st][ww] * e;
            A  += cmbA[st][ww][d] * e;
        }
        out[(size_t)st * B * D + (size_t)g * D + d] = A * __builtin_amdgcn_rcpf(Ls);
    }
}

// ---------------------------------------------------------------------------
extern "C" void kernel_launch(void* const* d_in, const int* in_sizes, int n_in,
                              void* d_out, int out_size, void* d_ws, size_t ws_size,
                              hipStream_t stream) {
    const float* xI    = (const float*)d_in[0];
    const float* xV    = (const float*)d_in[1];
    const float* Wu    = (const float*)d_in[2];
    const float* bu    = (const float*)d_in[3];
    const float* Wv    = (const float*)d_in[4];
    const float* We    = (const float*)d_in[5];
    // d_in[6] = seg_ids (unused: segments contiguous, last_nodes suffices)
    const int*   lastn = (const int*)d_in[7];
    const int B = in_sizes[7];               // 8192

    float*  cIb   = (float*)d_ws;
    float*  cVb   = cIb + (size_t)B * D;
    short8* fragW = (short8*)(cVb + (size_t)B * D);

    pack_wu<<<8, 256, 0, stream>>>(Wu, fragW);
    gate_k<<<(B + 15) / 16, 256, 0, stream>>>(xI, xV, Wv, bu, lastn, cIb, cVb, B);
    attn_main<<<B, 256, 0, stream>>>(xI, xV, We, lastn, cIb, cVb, fragW,
                                     (float*)d_out, B);
}

// Round 7
// 220.418 us; speedup vs baseline: 1.5231x; 1.0019x over previous
//
#include <hip/hip_runtime.h>
#include <stdint.h>

typedef short short8 __attribute__((ext_vector_type(8)));
typedef float f32x4 __attribute__((ext_vector_type(4)));

#define D 128
#define LOG2E 1.44269504088896340736f
#define GPB 4   // graphs per block (persistent-ish; grid = B/GPB)

__device__ __forceinline__ unsigned short f2bf(float f) {
    union { float f; unsigned u; } v; v.f = f;
    unsigned u = v.u;
    unsigned r = (u + 0x7FFFu + ((u >> 16) & 1u)) >> 16;  // RNE
    return (unsigned short)r;
}

// pack two f32 -> one u32 of two bf16 (round-half-up via +0x8000, then v_perm)
__device__ __forceinline__ unsigned packbf(float x, float y) {
    unsigned ux = __float_as_uint(x) + 0x8000u;
    unsigned uy = __float_as_uint(y) + 0x8000u;
    return __builtin_amdgcn_perm(uy, ux, 0x07060302u);
}

// DPP butterfly add within 16-lane groups (verified round 5/6).
template <int C>
__device__ __forceinline__ float dpp_add(float x) {
    int y = __builtin_amdgcn_update_dpp(0, __float_as_int(x), C, 0xF, 0xF, true);
    return x + __int_as_float(y);
}
__device__ __forceinline__ float red16(float x) {
    x = dpp_add<0xB1>(x);
    x = dpp_add<0x4E>(x);
    x = dpp_add<0x141>(x);
    x = dpp_add<0x140>(x);
    return x;
}

// ---------------------------------------------------------------------------
// Kernel 1: pre-pack (Wu * log2e) as bf16 MFMA B-fragments.
// t = nt*256 + kk*64 + lane holds B[k][col], col = nt*16+(lane&15),
// k = kk*32+(lane>>4)*8+j  (B[k][col] = Wu[col][k], u = f @ Wu^T)
// ---------------------------------------------------------------------------
__global__ __launch_bounds__(256) void pack_wu(const float* __restrict__ Wu,
                                               short8* __restrict__ frag) {
    int tid = blockIdx.x * 256 + threadIdx.x;
    int nt = tid >> 8, kk = (tid >> 6) & 3, l = tid & 63;
    int col = nt * 16 + (l & 15);
    int kb  = kk * 32 + ((l >> 4) * 8);
    short8 o;
#pragma unroll
    for (int j = 0; j < 8; ++j) o[j] = (short)f2bf(Wu[col * D + kb + j] * LOG2E);
    frag[tid] = o;
}

// ---------------------------------------------------------------------------
// Kernel 2: per-graph gate factors  c = 2^{-(Wv·x_last + bu)·log2e}.
// 16 graphs per block; Wv stays L1/L2-hot. (Validated round 5.)
// ---------------------------------------------------------------------------
__global__ __launch_bounds__(256) void gate_k(const float* __restrict__ xI,
                                              const float* __restrict__ xV,
                                              const float* __restrict__ Wv,
                                              const float* __restrict__ bu,
                                              const int* __restrict__ lastn,
                                              float* __restrict__ cIb,
                                              float* __restrict__ cVb, int B) {
    __shared__ __align__(16) float xs[4][2][D];
    int t = threadIdx.x, h = t & 127, st = t >> 7;
    float bias = bu[h];
    const float4* wv4 = (const float4*)(Wv + (size_t)h * D);
    const float* src = st ? xV : xI;
    float* dst = st ? cVb : cIb;
    int g0 = blockIdx.x * 16;
    for (int p = 0; p < 4; ++p) {
        int gb = g0 + p * 4;
#pragma unroll
        for (int j = 0; j < 4; ++j) {
            int gg = gb + j; if (gg >= B) gg = B - 1;
            xs[j][st][h] = src[(size_t)lastn[gg] * D + h];
        }
        __syncthreads();
        const float4* x0 = (const float4*)xs[0][st];
        const float4* x1 = (const float4*)xs[1][st];
        const float4* x2 = (const float4*)xs[2][st];
        const float4* x3 = (const float4*)xs[3][st];
        float a0 = 0.f, a1 = 0.f, a2 = 0.f, a3 = 0.f;
#pragma unroll
        for (int i = 0; i < 32; ++i) {
            float4 w = wv4[i], b;
            b = x0[i]; a0 += w.x*b.x + w.y*b.y + w.z*b.z + w.w*b.w;
            b = x1[i]; a1 += w.x*b.x + w.y*b.y + w.z*b.z + w.w*b.w;
            b = x2[i]; a2 += w.x*b.x + w.y*b.y + w.z*b.z + w.w*b.w;
            b = x3[i]; a3 += w.x*b.x + w.y*b.y + w.z*b.z + w.w*b.w;
        }
        if (gb + 0 < B) dst[(size_t)(gb+0)*D + h] = __builtin_amdgcn_exp2f(-(a0+bias)*LOG2E);
        if (gb + 1 < B) dst[(size_t)(gb+1)*D + h] = __builtin_amdgcn_exp2f(-(a1+bias)*LOG2E);
        if (gb + 2 < B) dst[(size_t)(gb+2)*D + h] = __builtin_amdgcn_exp2f(-(a2+bias)*LOG2E);
        if (gb + 3 < B) dst[(size_t)(gb+3)*D + h] = __builtin_amdgcn_exp2f(-(a3+bias)*LOG2E);
        __syncthreads();
    }
}

// ---------------------------------------------------------------------------
// Kernel 3: fused main. Persistent-ish: GPB graphs per block (contiguous
// node ranges), bfrag staged ONCE per block. Per graph: 4 waves stride
// 16-row chunks; A-fragments gathered directly from global (line-coalesced,
// read-once); accumulate re-reads hit L1/L2 as float2 (dims 2*lane,2*lane+1).
// ---------------------------------------------------------------------------
__global__ __launch_bounds__(256) void attn_main(
    const float* __restrict__ xI, const float* __restrict__ xV,
    const float* __restrict__ We, const int* __restrict__ lastn,
    const float* __restrict__ cIb, const float* __restrict__ cVb,
    const short8* __restrict__ fragG, float* __restrict__ out, int B) {
    __shared__ short8 bfrag[2048];                // 32 KB Wu fragments
    __shared__ __align__(16) float wt[4][16][2];  // per-wave weight table
    __shared__ float cmbA[2][4][D];               // combine
    __shared__ float cmbM[2][4], cmbL[2][4];

    int t = threadIdx.x, lane = t & 63, w = t >> 6;

    {   // stage Wu fragments once per block (contiguous 16B/lane)
        const uint4* srcf = (const uint4*)fragG;
        uint4* dst = (uint4*)bfrag;
#pragma unroll
        for (int i = 0; i < 8; ++i) dst[i * 256 + t] = srcf[i * 256 + t];
    }
    float WeR[8];                                 // graph-independent
#pragma unroll
    for (int nt = 0; nt < 8; ++nt) WeR[nt] = We[nt * 16 + (lane & 15)] * LOG2E;
    __syncthreads();

    int g0 = blockIdx.x * GPB;
    int sNext = (g0 == 0) ? 0 : (lastn[g0 - 1] + 1);

    for (int gi = 0; gi < GPB; ++gi) {
        int g = g0 + gi;
        int s = sNext;
        int e = lastn[g] + 1;
        sNext = e;
        int n = e - s;                            // >= 1

        float cIr[8], cVr[8];
#pragma unroll
        for (int nt = 0; nt < 8; ++nt) {
            int col = nt * 16 + (lane & 15);
            cIr[nt] = cIb[(size_t)g * D + col];
            cVr[nt] = cVb[(size_t)g * D + col];
        }

        float mI = -__builtin_inff(), mV = -__builtin_inff();
        float lIs = 0.f, lVs = 0.f;
        float aI0 = 0.f, aI1 = 0.f, aV0 = 0.f, aV1 = 0.f;

        int ch = (n + 15) >> 4;
        int total = 2 * ch;

        for (int c = w; c < total; c += 4) {
            int hf = (c >= ch) ? 1 : 0;
            const float* srcs = (hf ? xV : xI) + ((size_t)s << 7);
            int base = (c - hf * ch) << 4;

            // ---- A fragments direct from global: row = lane&15,
            //      dims = (lane>>4)*8 + kk*32 + j ----
            int arow = base + (lane & 15);
            if (arow > n - 1) arow = n - 1;       // clamp (masked later)
            const float* rp = srcs + ((size_t)arow << 7) + ((lane >> 4) << 3);
            short8 af[4];
#pragma unroll
            for (int kk = 0; kk < 4; ++kk) {
                float4 f0 = *(const float4*)(rp + kk * 32);
                float4 f1 = *(const float4*)(rp + kk * 32 + 4);
                union { unsigned u[4]; short8 s8; } cv;
                cv.u[0] = packbf(f0.x, f0.y);
                cv.u[1] = packbf(f0.z, f0.w);
                cv.u[2] = packbf(f1.x, f1.y);
                cv.u[3] = packbf(f1.z, f1.w);
                af[kk] = cv.s8;
            }

            // ---- GEMM + gate epilogue (shared exp2 + shared rcp) ----
            float pI[4] = {0.f, 0.f, 0.f, 0.f}, pV[4] = {0.f, 0.f, 0.f, 0.f};
#pragma unroll
            for (int nt = 0; nt < 8; ++nt) {
                f32x4 dacc = {0.f, 0.f, 0.f, 0.f};
#pragma unroll
                for (int kk = 0; kk < 4; ++kk)
                    dacc = __builtin_amdgcn_mfma_f32_16x16x32_bf16(
                        af[kk], bfrag[nt * 256 + kk * 64 + lane], dacc, 0, 0, 0);
#pragma unroll
                for (int q = 0; q < 4; ++q) {
                    float t2 = __builtin_amdgcn_exp2f(-dacc[q]);
                    float dI = fmaf(t2, cIr[nt], 1.f);
                    float dV = fmaf(t2, cVr[nt], 1.f);
                    float rr = __builtin_amdgcn_rcpf(dI * dV);
                    pI[q] = fmaf(WeR[nt], dV * rr, pI[q]);   // WeR/dI
                    pV[q] = fmaf(WeR[nt], dI * rr, pV[q]);   // WeR/dV
                }
            }
            // reduce across 16 lanes via DPP; mask invalid rows (tail only)
#pragma unroll
            for (int q = 0; q < 4; ++q) { pI[q] = red16(pI[q]); pV[q] = red16(pV[q]); }
            if (base + 16 > n) {
#pragma unroll
                for (int q = 0; q < 4; ++q) {
                    int r = ((lane >> 4) << 2) + q;
                    if (base + r >= n) { pI[q] = -__builtin_inff(); pV[q] = -__builtin_inff(); }
                }
            }
            float cmI = fmaxf(fmaxf(pI[0], pI[1]), fmaxf(pI[2], pI[3]));
            float cmV = fmaxf(fmaxf(pV[0], pV[1]), fmaxf(pV[2], pV[3]));
            cmI = fmaxf(cmI, __shfl_xor(cmI, 16)); cmI = fmaxf(cmI, __shfl_xor(cmI, 32));
            cmV = fmaxf(cmV, __shfl_xor(cmV, 16)); cmV = fmaxf(cmV, __shfl_xor(cmV, 32));

            float mnI = fmaxf(mI, cmI), mnV = fmaxf(mV, cmV);
            float scI = __builtin_amdgcn_exp2f(mI - mnI);
            float scV = __builtin_amdgcn_exp2f(mV - mnV);
            lIs *= scI; lVs *= scV;
            aI0 *= scI; aI1 *= scI; aV0 *= scV; aV1 *= scV;

            float wIq[4], wVq[4];
#pragma unroll
            for (int q = 0; q < 4; ++q) {
                wIq[q] = __builtin_amdgcn_exp2f(pI[q] - mnI);   // 0 for masked
                wVq[q] = __builtin_amdgcn_exp2f(pV[q] - mnV);
            }
            float sIq = wIq[0] + wIq[1] + wIq[2] + wIq[3];
            float sVq = wVq[0] + wVq[1] + wVq[2] + wVq[3];
            sIq += __shfl_xor(sIq, 16); sIq += __shfl_xor(sIq, 32);
            sVq += __shfl_xor(sVq, 16); sVq += __shfl_xor(sVq, 32);
            lIs += sIq; lVs += sVq;

            // publish weights to per-wave LDS table (wave-private, in-order)
            if ((lane & 15) == 0) {
                int gq = lane >> 4;
                float4 w0 = {wIq[0], wVq[0], wIq[1], wVq[1]};
                float4 w1 = {wIq[2], wVq[2], wIq[3], wVq[3]};
                *(float4*)&wt[w][gq * 4 + 0][0] = w0;
                *(float4*)&wt[w][gq * 4 + 2][0] = w1;
            }
            asm volatile("" ::: "memory");

            // ---- weighted accumulate; float2 re-reads (L1/L2-hot) ----
            const float2* s2 = (const float2*)srcs;
#pragma unroll
            for (int r = 0; r < 16; ++r) {
                int rr = base + r; if (rr > n - 1) rr = n - 1;
                float2 f = s2[((size_t)rr << 6) + lane];
                float2 wv = *(const float2*)&wt[w][r][0];
                aI0 = fmaf(wv.x, f.x, aI0); aI1 = fmaf(wv.x, f.y, aI1);
                aV0 = fmaf(wv.y, f.x, aV0); aV1 = fmaf(wv.y, f.y, aV1);
            }
            mI = mnI; mV = mnV;
        }

        // ---- cross-wave flash combine (dims 2*lane, 2*lane+1) ----
        __syncthreads();   // WAR: previous graph's combine reads done
        {
            float2 vI = {aI0, aI1}, vV = {aV0, aV1};
            *(float2*)&cmbA[0][w][lane * 2] = vI;
            *(float2*)&cmbA[1][w][lane * 2] = vV;
        }
        if (lane == 0) {
            cmbM[0][w] = mI; cmbL[0][w] = lIs;
            cmbM[1][w] = mV; cmbL[1][w] = lVs;
        }
        __syncthreads();
        {
            int st = t >> 7, d = t & 127;
            float M = fmaxf(fmaxf(cmbM[st][0], cmbM[st][1]),
                            fmaxf(cmbM[st][2], cmbM[st][3]));
            float Ls = 0.f, A = 0.f;
#pragma unroll
            for (int ww = 0; ww < 4; ++ww) {
                float e2 = __builtin_amdgcn_exp2f(cmbM[st][ww] - M);  // 0 if idle
                Ls += cmbL[st][ww] * e2;
                A  += cmbA[st][ww][d] * e2;
            }
            out[(size_t)st * B * D + (size_t)g * D + d] = A * __builtin_amdgcn_rcpf(Ls);
        }
    }
}

// ---------------------------------------------------------------------------
extern "C" void kernel_launch(void* const* d_in, const int* in_sizes, int n_in,
                              void* d_out, int out_size, void* d_ws, size_t ws_size,
                              hipStream_t stream) {
    const float* xI    = (const float*)d_in[0];
    const float* xV    = (const float*)d_in[1];
    const float* Wu    = (const float*)d_in[2];
    const float* bu    = (const float*)d_in[3];
    const float* Wv    = (const float*)d_in[4];
    const float* We    = (const float*)d_in[5];
    // d_in[6] = seg_ids (unused: segments contiguous, last_nodes suffices)
    const int*   lastn = (const int*)d_in[7];
    const int B = in_sizes[7];               // 8192

    float*  cIb   = (float*)d_ws;
    float*  cVb   = cIb + (size_t)B * D;
    short8* fragW = (short8*)(cVb + (size_t)B * D);

    pack_wu<<<8, 256, 0, stream>>>(Wu, fragW);
    gate_k<<<(B + 15) / 16, 256, 0, stream>>>(xI, xV, Wv, bu, lastn, cIb, cVb, B);
    attn_main<<<B / GPB, 256, 0, stream>>>(xI, xV, We, lastn, cIb, cVb, fragW,
                                           (float*)d_out, B);
}